// Round 12
// baseline (220.045 us; speedup 1.0000x reference)
//
#include <hip/hip_runtime.h>
#include <math.h>

#define BATCH 128
#define HH 256
#define WW 256
#define HW (HH * WW)
#define HW4 (HW / 4)     // 16384 float4 per plane
#define NKPT 68
#define BPB 32           // blocks per batch (2 chunks each)
#define FLAG_STRIDE 32   // one flag per 128-B cacheline
#define FLAGS_BYTES (BATCH * FLAG_STRIDE * 4)

typedef float fx4 __attribute__((ext_vector_type(4)));

__device__ inline double wave_sum64(double v) {
#pragma unroll
    for (int off = 32; off > 0; off >>= 1) v += __shfl_xor(v, off);
    return v;
}

// ---------------------------------------------------------------------------
// Per-batch similarity transform, wave-parallel (verified R9 math, absmax
// 0.03125): lane-parallel gather + single butterfly-reduction pass; lane 0
// computes R = polar(Hm^T) via det-scaled Newton iteration (= SVD's V U^T).
// ---------------------------------------------------------------------------
__device__ void tform_wave(int tb, int lane, const float* __restrict__ Offset,
                           const float* __restrict__ Posmap,
                           const float* __restrict__ meanp,
                           const int* __restrict__ uv, float* __restrict__ RT) {
    const float* offb = Offset + (size_t)tb * 3 * HW;
    const float* dstb = Posmap + (size_t)tb * 3 * HW;
    const bool has1 = lane < (NKPT - 64);

    double s0[3], d0[3], s1[3] = {0, 0, 0}, d1[3] = {0, 0, 0};
    {
        const int q0 = uv[lane * 2 + 0] * WW + uv[lane * 2 + 1];
#pragma unroll
        for (int i = 0; i < 3; i++) {
            s0[i] = (double)offb[(size_t)i * HW + q0] * 6.0 +
                    (double)meanp[(size_t)i * HW + q0];
            d0[i] = (double)dstb[(size_t)i * HW + q0];
        }
        if (has1) {
            const int k1 = lane + 64;
            const int q1 = uv[k1 * 2 + 0] * WW + uv[k1 * 2 + 1];
#pragma unroll
            for (int i = 0; i < 3; i++) {
                s1[i] = (double)offb[(size_t)i * HW + q1] * 6.0 +
                        (double)meanp[(size_t)i * HW + q1];
                d1[i] = (double)dstb[(size_t)i * HW + q1];
            }
        }
    }

    double s33[3], d33[3];
#pragma unroll
    for (int i = 0; i < 3; i++) {
        s33[i] = __shfl(s0[i], 33);
        d33[i] = __shfl(d0[i], 33);
    }

    double ns0 = 0, nd0 = 0, ns1 = 0, nd1 = 0;
    double ssum[3], dsum[3], P[3][3];
#pragma unroll
    for (int i = 0; i < 3; i++) {
        double es = s0[i] - s33[i], ed = d0[i] - d33[i];
        ns0 += es * es;
        nd0 += ed * ed;
        es = s1[i] - s33[i];
        ed = d1[i] - d33[i];
        ns1 += es * es;
        nd1 += ed * ed;
        ssum[i] = s0[i] + s1[i];
        dsum[i] = d0[i] + d1[i];
#pragma unroll
        for (int j = 0; j < 3; j++) P[i][j] = s0[i] * d0[j] + s1[i] * d1[j];
    }
    double sd1p = sqrt(ns0) + (has1 ? sqrt(ns1) : 0.0);
    double sd2p = sqrt(nd0) + (has1 ? sqrt(nd1) : 0.0);

    const double sd1 = wave_sum64(sd1p);
    const double sd2 = wave_sum64(sd2p);
#pragma unroll
    for (int i = 0; i < 3; i++) {
        ssum[i] = wave_sum64(ssum[i]);
        dsum[i] = wave_sum64(dsum[i]);
    }
#pragma unroll
    for (int i = 0; i < 3; i++)
#pragma unroll
        for (int j = 0; j < 3; j++) P[i][j] = wave_sum64(P[i][j]);

    if (lane != 0) return;

    const double s = sd2 / sd1;
    double sbar[3], dbar[3];
#pragma unroll
    for (int i = 0; i < 3; i++) {
        sbar[i] = ssum[i] / NKPT;
        dbar[i] = dsum[i] / NKPT;
    }
    double Hm[3][3];
#pragma unroll
    for (int i = 0; i < 3; i++)
#pragma unroll
        for (int j = 0; j < 3; j++)
            Hm[i][j] = P[i][j] - (double)NKPT * sbar[i] * dbar[j];

    double X[3][3];
#pragma unroll
    for (int i = 0; i < 3; i++)
#pragma unroll
        for (int j = 0; j < 3; j++) X[i][j] = Hm[j][i];

#pragma unroll
    for (int it = 0; it < 9; ++it) {
        double C[3][3];
        C[0][0] = X[1][1] * X[2][2] - X[1][2] * X[2][1];
        C[0][1] = X[1][2] * X[2][0] - X[1][0] * X[2][2];
        C[0][2] = X[1][0] * X[2][1] - X[1][1] * X[2][0];
        C[1][0] = X[0][2] * X[2][1] - X[0][1] * X[2][2];
        C[1][1] = X[0][0] * X[2][2] - X[0][2] * X[2][0];
        C[1][2] = X[0][1] * X[2][0] - X[0][0] * X[2][1];
        C[2][0] = X[0][1] * X[1][2] - X[0][2] * X[1][1];
        C[2][1] = X[0][2] * X[1][0] - X[0][0] * X[1][2];
        C[2][2] = X[0][0] * X[1][1] - X[0][1] * X[1][0];
        double det =
            X[0][0] * C[0][0] + X[0][1] * C[0][1] + X[0][2] * C[0][2];
        double ad = fabs(det);
        if (ad < 1e-250) ad = 1e-250;
        const double mu = 1.0 / cbrt(ad);
        const double inv = 1.0 / (mu * det);
#pragma unroll
        for (int i = 0; i < 3; i++)
#pragma unroll
            for (int j = 0; j < 3; j++)
                X[i][j] = 0.5 * (mu * X[i][j] + C[i][j] * inv);
    }

    float* rt = RT + tb * 12;
    for (int j = 0; j < 3; j++) {
        for (int i = 0; i < 3; i++) rt[j * 3 + i] = (float)(X[j][i] * s);
        double tj = dbar[j];
        for (int i = 0; i < 3; i++) tj -= s * sbar[i] * X[j][i];
        rt[9 + j] = (float)tj;
    }
}

// ---------------------------------------------------------------------------
// Fused kernel, 4096 blocks (R9's proven 2-chunk apply engine). Per batch the
// first-arriving block claims the tform via atomicCAS on a CACHELINE-STRIDED
// flag, computes it on wave 0, release-publishes flag=2. Other blocks of the
// batch poll with ~0.85 us s_sleep backoff (<=32 resident pollers per line,
// ~40 polls/us/line — no coherence-point collapse, unlike R8's packed flags
// + tight spin). Claimant is resident by construction => deadlock-free under
// any dispatch order.
// ---------------------------------------------------------------------------
__global__ __launch_bounds__(256, 4) void fused_kernel(
    const float* __restrict__ Offset, const float* __restrict__ Posmap,
    const float* __restrict__ meanp, const int* __restrict__ uv,
    float* __restrict__ Out, float* __restrict__ WS) {
    int* flags = (int*)WS;                              // strided, zeroed/call
    float* RT = WS + FLAGS_BYTES / 4;                   // 128*12 floats

    const int blk = blockIdx.x;
    const int tid = threadIdx.x;
    const int b = blk / BPB;
    const int w = blk % BPB;
    const int p0 = w * 512 + tid;
    const int p1 = p0 + 256;
    const size_t base = (size_t)b * 3 * HW4;
    int* flag = &flags[b * FLAG_STRIDE];

    const fx4* Off4 = (const fx4*)Offset;
    const fx4* Mean4 = (const fx4*)meanp;
    fx4* Out4 = (fx4*)Out;

    __shared__ int sclaim;
    if (tid == 0) sclaim = (atomicCAS(flag, 0, 1) == 0) ? 1 : 0;
    __syncthreads();

    if (sclaim) {
        if (tid < 64) tform_wave(b, tid, Offset, Posmap, meanp, uv, RT);
        __syncthreads();
        if (tid == 0) {
            __threadfence();  // release RT to device scope
            __hip_atomic_store(flag, 2, __ATOMIC_RELEASE,
                               __HIP_MEMORY_SCOPE_AGENT);
        }
    } else if (tid == 0) {
        while (__hip_atomic_load(flag, __ATOMIC_ACQUIRE,
                                 __HIP_MEMORY_SCOPE_AGENT) != 2) {
            __builtin_amdgcn_s_sleep(32);  // ~2048 cycles between polls
        }
    }
    __syncthreads();

    // --- proven R9 2-chunk apply ---
    fx4 a0 = Off4[base + p0];
    fx4 a1 = Off4[base + HW4 + p0];
    fx4 a2 = Off4[base + 2 * HW4 + p0];
    fx4 b0 = Off4[base + p1];
    fx4 b1 = Off4[base + HW4 + p1];
    fx4 b2 = Off4[base + 2 * HW4 + p1];
    fx4 ma0 = Mean4[p0];
    fx4 ma1 = Mean4[HW4 + p0];
    fx4 ma2 = Mean4[2 * HW4 + p0];
    fx4 mb0 = Mean4[p1];
    fx4 mb1 = Mean4[HW4 + p1];
    fx4 mb2 = Mean4[2 * HW4 + p1];

    const float* rt = RT + b * 12;
    const float r00 = rt[0], r01 = rt[1], r02 = rt[2];
    const float r10 = rt[3], r11 = rt[4], r12 = rt[5];
    const float r20 = rt[6], r21 = rt[7], r22 = rt[8];
    const float t0 = rt[9], t1 = rt[10], t2 = rt[11];

    fx4 y0, y1, y2, z0, z1, z2;
#pragma unroll
    for (int e = 0; e < 4; e++) {
        float x0 = fmaf(a0[e], 6.0f, ma0[e]);
        float x1 = fmaf(a1[e], 6.0f, ma1[e]);
        float x2 = fmaf(a2[e], 6.0f, ma2[e]);
        y0[e] = fmaf(x0, r00, fmaf(x1, r01, fmaf(x2, r02, t0)));
        y1[e] = fmaf(x0, r10, fmaf(x1, r11, fmaf(x2, r12, t1)));
        y2[e] = fmaf(x0, r20, fmaf(x1, r21, fmaf(x2, r22, t2)));
        float u0 = fmaf(b0[e], 6.0f, mb0[e]);
        float u1 = fmaf(b1[e], 6.0f, mb1[e]);
        float u2 = fmaf(b2[e], 6.0f, mb2[e]);
        z0[e] = fmaf(u0, r00, fmaf(u1, r01, fmaf(u2, r02, t0)));
        z1[e] = fmaf(u0, r10, fmaf(u1, r11, fmaf(u2, r12, t1)));
        z2[e] = fmaf(u0, r20, fmaf(u1, r21, fmaf(u2, r22, t2)));
    }

    __builtin_nontemporal_store(y0, &Out4[base + p0]);
    __builtin_nontemporal_store(y1, &Out4[base + HW4 + p0]);
    __builtin_nontemporal_store(y2, &Out4[base + 2 * HW4 + p0]);
    __builtin_nontemporal_store(z0, &Out4[base + p1]);
    __builtin_nontemporal_store(z1, &Out4[base + HW4 + p1]);
    __builtin_nontemporal_store(z2, &Out4[base + 2 * HW4 + p1]);
}

extern "C" void kernel_launch(void* const* d_in, const int* in_sizes, int n_in,
                              void* d_out, int out_size, void* d_ws,
                              size_t ws_size, hipStream_t stream) {
    const float* Offset = (const float*)d_in[0];
    const float* Posmap = (const float*)d_in[1];
    const float* meanp = (const float*)d_in[2];
    const int* uv = (const int*)d_in[3];
    float* out = (float*)d_out;
    float* WS = (float*)d_ws;  // [strided flags 16KB][RT 128*12 floats]

    hipMemsetAsync(WS, 0, FLAGS_BYTES, stream);
    fused_kernel<<<BATCH * BPB, 256, 0, stream>>>(Offset, Posmap, meanp, uv,
                                                  out, WS);
}

// Round 13
// 42.070 us; speedup vs baseline: 5.2304x; 5.2304x over previous
//
#include <hip/hip_runtime.h>
#include <math.h>

#define BATCH 128
#define HH 256
#define WW 256
#define HW (HH * WW)
#define HW4 (HW / 4)   // 16384 float4 per plane
#define NKPT 68

typedef float fx4 __attribute__((ext_vector_type(4)));

__device__ inline double wave_sum64(double v) {
#pragma unroll
    for (int off = 32; off > 0; off >>= 1) v += __shfl_xor(v, off);
    return v;
}

// ---------------------------------------------------------------------------
// Kernel A: per-batch similarity transform (verified R9: absmax 0.03125).
// One wave per batch. Lane-parallel gather + one butterfly-reduction pass;
// lane 0 computes R = polar(Hm^T) via det-scaled Newton iteration.
// ---------------------------------------------------------------------------
__global__ __launch_bounds__(64, 1) void tform_kernel(
    const float* __restrict__ Offset, const float* __restrict__ Posmap,
    const float* __restrict__ meanp, const int* __restrict__ uv,
    float* __restrict__ RT) {
    const int b = blockIdx.x;
    const int lane = threadIdx.x;
    const float* offb = Offset + (size_t)b * 3 * HW;
    const float* dstb = Posmap + (size_t)b * 3 * HW;
    const bool has1 = lane < (NKPT - 64);

    double s0[3], d0[3], s1[3] = {0, 0, 0}, d1[3] = {0, 0, 0};
    {
        const int q0 = uv[lane * 2 + 0] * WW + uv[lane * 2 + 1];
#pragma unroll
        for (int i = 0; i < 3; i++) {
            s0[i] = (double)offb[(size_t)i * HW + q0] * 6.0 +
                    (double)meanp[(size_t)i * HW + q0];
            d0[i] = (double)dstb[(size_t)i * HW + q0];
        }
        if (has1) {
            const int k1 = lane + 64;
            const int q1 = uv[k1 * 2 + 0] * WW + uv[k1 * 2 + 1];
#pragma unroll
            for (int i = 0; i < 3; i++) {
                s1[i] = (double)offb[(size_t)i * HW + q1] * 6.0 +
                        (double)meanp[(size_t)i * HW + q1];
                d1[i] = (double)dstb[(size_t)i * HW + q1];
            }
        }
    }

    double s33[3], d33[3];
#pragma unroll
    for (int i = 0; i < 3; i++) {
        s33[i] = __shfl(s0[i], 33);
        d33[i] = __shfl(d0[i], 33);
    }

    double ns0 = 0, nd0 = 0, ns1 = 0, nd1 = 0;
    double ssum[3], dsum[3], P[3][3];
#pragma unroll
    for (int i = 0; i < 3; i++) {
        double es = s0[i] - s33[i], ed = d0[i] - d33[i];
        ns0 += es * es;
        nd0 += ed * ed;
        es = s1[i] - s33[i];
        ed = d1[i] - d33[i];
        ns1 += es * es;
        nd1 += ed * ed;
        ssum[i] = s0[i] + s1[i];
        dsum[i] = d0[i] + d1[i];
#pragma unroll
        for (int j = 0; j < 3; j++) P[i][j] = s0[i] * d0[j] + s1[i] * d1[j];
    }
    double sd1p = sqrt(ns0) + (has1 ? sqrt(ns1) : 0.0);
    double sd2p = sqrt(nd0) + (has1 ? sqrt(nd1) : 0.0);

    const double sd1 = wave_sum64(sd1p);
    const double sd2 = wave_sum64(sd2p);
#pragma unroll
    for (int i = 0; i < 3; i++) {
        ssum[i] = wave_sum64(ssum[i]);
        dsum[i] = wave_sum64(dsum[i]);
    }
#pragma unroll
    for (int i = 0; i < 3; i++)
#pragma unroll
        for (int j = 0; j < 3; j++) P[i][j] = wave_sum64(P[i][j]);

    if (lane != 0) return;

    const double s = sd2 / sd1;
    double sbar[3], dbar[3];
#pragma unroll
    for (int i = 0; i < 3; i++) {
        sbar[i] = ssum[i] / NKPT;
        dbar[i] = dsum[i] / NKPT;
    }
    double Hm[3][3];
#pragma unroll
    for (int i = 0; i < 3; i++)
#pragma unroll
        for (int j = 0; j < 3; j++)
            Hm[i][j] = P[i][j] - (double)NKPT * sbar[i] * dbar[j];

    double X[3][3];
#pragma unroll
    for (int i = 0; i < 3; i++)
#pragma unroll
        for (int j = 0; j < 3; j++) X[i][j] = Hm[j][i];

#pragma unroll
    for (int it = 0; it < 9; ++it) {
        double C[3][3];
        C[0][0] = X[1][1] * X[2][2] - X[1][2] * X[2][1];
        C[0][1] = X[1][2] * X[2][0] - X[1][0] * X[2][2];
        C[0][2] = X[1][0] * X[2][1] - X[1][1] * X[2][0];
        C[1][0] = X[0][2] * X[2][1] - X[0][1] * X[2][2];
        C[1][1] = X[0][0] * X[2][2] - X[0][2] * X[2][0];
        C[1][2] = X[0][1] * X[2][0] - X[0][0] * X[2][1];
        C[2][0] = X[0][1] * X[1][2] - X[0][2] * X[1][1];
        C[2][1] = X[0][2] * X[1][0] - X[0][0] * X[1][2];
        C[2][2] = X[0][0] * X[1][1] - X[0][1] * X[1][0];
        double det =
            X[0][0] * C[0][0] + X[0][1] * C[0][1] + X[0][2] * C[0][2];
        double ad = fabs(det);
        if (ad < 1e-250) ad = 1e-250;
        const double mu = 1.0 / cbrt(ad);
        const double inv = 1.0 / (mu * det);
#pragma unroll
        for (int i = 0; i < 3; i++)
#pragma unroll
            for (int j = 0; j < 3; j++)
                X[i][j] = 0.5 * (mu * X[i][j] + C[i][j] * inv);
    }

    float* rt = RT + b * 12;
    for (int j = 0; j < 3; j++) {
        for (int i = 0; i < 3; i++) rt[j * 3 + i] = (float)(X[j][i] * s);
        double tj = dbar[j];
        for (int i = 0; i < 3; i++) tj -= s * sbar[i] * X[j][i];
        rt[9 + j] = (float)tj;
    }
}

// ---------------------------------------------------------------------------
// Kernel B: out[b,j,h,w] = sum_i (Offset[b,i,h,w]*6 + mean[i,h,w]) * Rs[j][i]
//                          + t[j]
// R9's proven 2-chunk geometry (4096 blocks), but __launch_bounds__(256,8):
// VGPR is 32-36 so 8 blocks/CU fit -> 32 waves/CU, doubling aggregate
// outstanding loads (the BW*latency product needs ~22KB/CU in flight; 16
// waves at the compiler's 2-3 outstanding loads/wave was marginal).
// ---------------------------------------------------------------------------
__global__ __launch_bounds__(256, 8) void apply_kernel(
    const fx4* __restrict__ Off, const fx4* __restrict__ Mean,
    const float* __restrict__ RT, fx4* __restrict__ Out) {
    const int PAIRS = HW4 / 512;  // 32 chunk-pairs per batch
    const int b = blockIdx.x / PAIRS;
    const int w = blockIdx.x % PAIRS;
    const int p0 = w * 512 + threadIdx.x;
    const int p1 = p0 + 256;
    const size_t base = (size_t)b * 3 * HW4;

    fx4 a0 = Off[base + p0];
    fx4 a1 = Off[base + HW4 + p0];
    fx4 a2 = Off[base + 2 * HW4 + p0];
    fx4 b0 = Off[base + p1];
    fx4 b1 = Off[base + HW4 + p1];
    fx4 b2 = Off[base + 2 * HW4 + p1];
    fx4 ma0 = Mean[p0];
    fx4 ma1 = Mean[HW4 + p0];
    fx4 ma2 = Mean[2 * HW4 + p0];
    fx4 mb0 = Mean[p1];
    fx4 mb1 = Mean[HW4 + p1];
    fx4 mb2 = Mean[2 * HW4 + p1];

    const float* rt = RT + b * 12;
    const float r00 = rt[0], r01 = rt[1], r02 = rt[2];
    const float r10 = rt[3], r11 = rt[4], r12 = rt[5];
    const float r20 = rt[6], r21 = rt[7], r22 = rt[8];
    const float t0 = rt[9], t1 = rt[10], t2 = rt[11];

    fx4 y0, y1, y2, z0, z1, z2;
#pragma unroll
    for (int e = 0; e < 4; e++) {
        float x0 = fmaf(a0[e], 6.0f, ma0[e]);
        float x1 = fmaf(a1[e], 6.0f, ma1[e]);
        float x2 = fmaf(a2[e], 6.0f, ma2[e]);
        y0[e] = fmaf(x0, r00, fmaf(x1, r01, fmaf(x2, r02, t0)));
        y1[e] = fmaf(x0, r10, fmaf(x1, r11, fmaf(x2, r12, t1)));
        y2[e] = fmaf(x0, r20, fmaf(x1, r21, fmaf(x2, r22, t2)));
        float u0 = fmaf(b0[e], 6.0f, mb0[e]);
        float u1 = fmaf(b1[e], 6.0f, mb1[e]);
        float u2 = fmaf(b2[e], 6.0f, mb2[e]);
        z0[e] = fmaf(u0, r00, fmaf(u1, r01, fmaf(u2, r02, t0)));
        z1[e] = fmaf(u0, r10, fmaf(u1, r11, fmaf(u2, r12, t1)));
        z2[e] = fmaf(u0, r20, fmaf(u1, r21, fmaf(u2, r22, t2)));
    }

    __builtin_nontemporal_store(y0, &Out[base + p0]);
    __builtin_nontemporal_store(y1, &Out[base + HW4 + p0]);
    __builtin_nontemporal_store(y2, &Out[base + 2 * HW4 + p0]);
    __builtin_nontemporal_store(z0, &Out[base + p1]);
    __builtin_nontemporal_store(z1, &Out[base + HW4 + p1]);
    __builtin_nontemporal_store(z2, &Out[base + 2 * HW4 + p1]);
}

extern "C" void kernel_launch(void* const* d_in, const int* in_sizes, int n_in,
                              void* d_out, int out_size, void* d_ws,
                              size_t ws_size, hipStream_t stream) {
    const float* Offset = (const float*)d_in[0];
    const float* Posmap = (const float*)d_in[1];
    const float* meanp = (const float*)d_in[2];
    const int* uv = (const int*)d_in[3];
    float* out = (float*)d_out;
    float* RT = (float*)d_ws;  // 128 * 12 floats

    tform_kernel<<<BATCH, 64, 0, stream>>>(Offset, Posmap, meanp, uv, RT);
    apply_kernel<<<BATCH * (HW4 / 512), 256, 0, stream>>>(
        (const fx4*)Offset, (const fx4*)meanp, RT, (fx4*)out);
}